// Round 7
// baseline (89.801 us; speedup 1.0000x reference)
//
#include <hip/hip_runtime.h>
#include <hip/hip_bf16.h>

// R6 source UNCHANGED except kernel_launch enqueues main 4x (idempotent) to
// measure T_main from the dur_us increment: T_main = (dur7 - 35.5)/3.

#define CKK 288
#define SJ  296   // padded j-stride for u_lds (bf16 elems)

typedef __attribute__((ext_vector_type(8))) short short8;
typedef __attribute__((ext_vector_type(4))) float f32x4;

// ws layout in bf16 elements
#define W2F_OFF 0               // [64 w8][9 kb][64 lane][8] fragment order
#define W1B_OFF 294912          // [32][288] row order
#define B2B_OFF (294912 + 9216) // [32][288] row order
#define WS_ELEMS (294912 + 9216 + 9216)

__global__ __launch_bounds__(256) void prep_kernel(
    const float* __restrict__ W1, const float* __restrict__ W2,
    const float* __restrict__ b2, __hip_bfloat16* __restrict__ ws)
{
    int idx = blockIdx.x * 256 + threadIdx.x;
    if (idx < 294912) {
        int e  = idx & 7;
        int l  = (idx >> 3) & 63;
        int ck = idx >> 9;              // 0..575 = w8*9 + kb
        int w8 = ck / 9, kb = ck - w8 * 9;
        int o  = w8 >> 1;
        int h  = (w8 & 1) * 16 + (l & 15);
        int j  = kb * 32 + ((l >> 4) << 3) + e;
        ws[W2F_OFF + idx] = __float2bfloat16(W2[(o * CKK + j) * 32 + h]);
    } else if (idx < 294912 + 9216) {
        int k = idx - 294912;
        ws[W1B_OFF + k] = __float2bfloat16(W1[k]);
    } else if (idx < WS_ELEMS) {
        int k = idx - (294912 + 9216);
        ws[B2B_OFF + k] = __float2bfloat16(b2[k]);
    }
}

__global__ __launch_bounds__(512) void dynaconv_main(
    const float* __restrict__ x,     // [2,32,64,64]
    const float* __restrict__ b1,    // [32]
    const float* __restrict__ bias,  // [32]
    const __hip_bfloat16* __restrict__ ws,
    float* __restrict__ out)         // [2,32,4096]
{
    __shared__ __hip_bfloat16 u_lds[32 * SJ];  // [p][j]
    __shared__ float hh_lds[32 * 33];          // [p][h]
    __shared__ float o_lds[32 * 33];           // [p][o], seeded with t+bias

    const int t  = threadIdx.x;
    const int w  = t >> 6;   // wave 0..7
    const int l  = t & 63;
    const int lg = l >> 4;   // k-group 0..3
    const int lr = l & 15;

    const int g0  = blockIdx.x * 32;  // first global pixel
    const int b   = g0 >> 12;
    const int l0  = g0 & 4095;
    const int y   = l0 >> 6;
    const int wx0 = l0 & 63;

    // ---- Phase A: fused unfold -> u_lds (bf16) ----
    #pragma unroll
    for (int k = 0; k < 18; ++k) {
        int idx = k * 512 + t;        // 9216 = 32p * 288j
        int j = idx >> 5, p = idx & 31;
        int c = j / 9, r = j - c * 9;
        int ki = r / 3, kj = r - ki * 3;
        int y2 = y + ki - 1;
        int x2 = wx0 + p + kj - 1;
        float v = 0.f;
        if ((unsigned)y2 < 64u && (unsigned)x2 < 64u)
            v = x[((b * 32 + c) * 64 + y2) * 64 + x2];
        u_lds[p * SJ + j] = __float2bfloat16(v);
    }
    __syncthreads();

    // ---- Phase B: waves 0-1: t+bias -> o_lds ; waves 2-3: hh -> hh_lds ----
    if (w < 4) {
        const __hip_bfloat16* Bmat = ws + ((w < 2) ? B2B_OFF : W1B_OFF);
        const int col = ((w & 1) * 16) + lr;   // o or h column
        f32x4 acc0 = {0.f, 0.f, 0.f, 0.f}, acc1 = {0.f, 0.f, 0.f, 0.f};
        #pragma unroll
        for (int kb = 0; kb < 9; ++kb) {
            short8 bf = *(const short8*)(Bmat + col * CKK + kb * 32 + lg * 8);
            short8 a0 = *(const short8*)(u_lds + lr * SJ + kb * 32 + lg * 8);
            short8 a1 = *(const short8*)(u_lds + (16 + lr) * SJ + kb * 32 + lg * 8);
            acc0 = __builtin_amdgcn_mfma_f32_16x16x32_bf16(a0, bf, acc0, 0, 0, 0);
            acc1 = __builtin_amdgcn_mfma_f32_16x16x32_bf16(a1, bf, acc1, 0, 0, 0);
        }
        if (w < 2) {
            float bv = bias[col];
            #pragma unroll
            for (int r = 0; r < 4; ++r) {
                o_lds[(lg * 4 + r) * 33 + col]        = acc0[r] + bv;
                o_lds[(16 + lg * 4 + r) * 33 + col]   = acc1[r] + bv;
            }
        } else {
            float b1v = b1[col];
            #pragma unroll
            for (int r = 0; r < 4; ++r) {
                hh_lds[(lg * 4 + r) * 33 + col]       = tanhf(acc0[r] + b1v);
                hh_lds[(16 + lg * 4 + r) * 33 + col]  = tanhf(acc1[r] + b1v);
            }
        }
    }
    __syncthreads();

    // ---- Phase C: main GEMM. wave w owns o = w*4..w*4+3 ----
    f32x4 acc[2][8];
    #pragma unroll
    for (int m = 0; m < 2; ++m)
        #pragma unroll
        for (int nf = 0; nf < 8; ++nf)
            acc[m][nf] = f32x4{0.f, 0.f, 0.f, 0.f};

    {
        const __hip_bfloat16* W2f = ws + W2F_OFF;
        short8 bcur[8];
        #pragma unroll
        for (int nf = 0; nf < 8; ++nf)
            bcur[nf] = *(const short8*)(W2f + (size_t)((w * 8 + nf) * 9 + 0) * 512 + l * 8);

        #pragma unroll
        for (int kb = 0; kb < 9; ++kb) {
            short8 a0 = *(const short8*)(u_lds + lr * SJ + kb * 32 + lg * 8);
            short8 a1 = *(const short8*)(u_lds + (16 + lr) * SJ + kb * 32 + lg * 8);
            short8 bnext[8];
            if (kb < 8) {
                #pragma unroll
                for (int nf = 0; nf < 8; ++nf)
                    bnext[nf] = *(const short8*)(W2f + (size_t)((w * 8 + nf) * 9 + kb + 1) * 512 + l * 8);
            }
            #pragma unroll
            for (int nf = 0; nf < 8; ++nf) {
                acc[0][nf] = __builtin_amdgcn_mfma_f32_16x16x32_bf16(a0, bcur[nf], acc[0][nf], 0, 0, 0);
                acc[1][nf] = __builtin_amdgcn_mfma_f32_16x16x32_bf16(a1, bcur[nf], acc[1][nf], 0, 0, 0);
            }
            if (kb < 8) {
                #pragma unroll
                for (int nf = 0; nf < 8; ++nf)
                    bcur[nf] = bnext[nf];
            }
        }
    }

    // ---- Epilogue ----
    #pragma unroll
    for (int ol = 0; ol < 4; ++ol) {
        const int o = w * 4 + ol;
        #pragma unroll
        for (int m = 0; m < 2; ++m) {
            #pragma unroll
            for (int r = 0; r < 4; ++r) {
                const int p = m * 16 + lg * 4 + r;
                float v = hh_lds[p * 33 + lr]      * acc[m][ol * 2][r]
                        + hh_lds[p * 33 + 16 + lr] * acc[m][ol * 2 + 1][r];
                v += __shfl_xor(v, 1);
                v += __shfl_xor(v, 2);
                v += __shfl_xor(v, 4);
                v += __shfl_xor(v, 8);
                if (lr == 0) o_lds[p * 33 + o] += v;
            }
        }
    }
    __syncthreads();

    // ---- Store ----
    #pragma unroll
    for (int k = 0; k < 2; ++k) {
        int idx = k * 512 + t;          // 1024 = 32o * 32p
        int o = idx >> 5, p = idx & 31;
        out[((size_t)(b * 32 + o)) * 4096 + l0 + p] = o_lds[p * 33 + o];
    }
}

extern "C" void kernel_launch(void* const* d_in, const int* in_sizes, int n_in,
                              void* d_out, int out_size, void* d_ws, size_t ws_size,
                              hipStream_t stream) {
    const float* x    = (const float*)d_in[0];
    const float* W1   = (const float*)d_in[1];
    const float* b1   = (const float*)d_in[2];
    const float* W2   = (const float*)d_in[3];
    const float* b2   = (const float*)d_in[4];
    const float* bias = (const float*)d_in[5];
    float* out = (float*)d_out;
    __hip_bfloat16* ws = (__hip_bfloat16*)d_ws;

    prep_kernel<<<(WS_ELEMS + 255) / 256, 256, 0, stream>>>(W1, W2, b2, ws);
    // Diagnostic: 4 identical (idempotent) main launches.
    // T_main = (dur_us_R7 - dur_us_R6) / 3.
    for (int rep = 0; rep < 4; ++rep)
        dynaconv_main<<<256, 512, 0, stream>>>(x, b1, bias, ws, out);
}

// Round 8
// 30.934 us; speedup vs baseline: 2.9030x; 2.9030x over previous
//
#include <hip/hip_runtime.h>
#include <hip/hip_bf16.h>

// R8: R6 structure with (1) main split over grid 1024 = 256 mt x 4 nt,
// 256 thr, 4 blocks/CU (occupancy fix for the 18us latency-bound main);
// (2) prep remapped source-linear (coalesced W2 reads, scattered writes).

#define CKK 288
#define SJ  296   // padded j-stride for u_lds (bf16 elems)

typedef __attribute__((ext_vector_type(8))) short short8;
typedef __attribute__((ext_vector_type(4))) float f32x4;

// ws layout in bf16 elements (626KB total, same as proven R6)
#define W2F_OFF 0               // [64 w8][9 kb][64 lane][8] fragment order
#define W1B_OFF 294912          // [32][288] row order
#define B2B_OFF (294912 + 9216) // [32][288] row order
#define WS_ELEMS (294912 + 9216 + 9216)

__global__ __launch_bounds__(256) void prep_kernel(
    const float* __restrict__ W1, const float* __restrict__ W2,
    const float* __restrict__ b2, __hip_bfloat16* __restrict__ ws)
{
    int s = blockIdx.x * 256 + threadIdx.x;
    if (s < 294912) {
        // source-linear: s -> (o,j,h); dest = inverse of R6 fragment mapping
        int o = s / 9216, rem = s - o * 9216;
        int j = rem >> 5, h = rem & 31;
        int w8 = o * 2 + (h >> 4);
        int kb = j >> 5;
        int l  = ((j >> 3) & 3) * 16 + (h & 15);
        int e  = j & 7;
        ws[W2F_OFF + (w8 * 9 + kb) * 512 + l * 8 + e] = __float2bfloat16(W2[s]);
    } else if (s < 294912 + 9216) {
        int k = s - 294912;
        ws[W1B_OFF + k] = __float2bfloat16(W1[k]);
    } else if (s < WS_ELEMS) {
        int k = s - (294912 + 9216);
        ws[B2B_OFF + k] = __float2bfloat16(b2[k]);
    }
}

__global__ __launch_bounds__(256, 4) void dynaconv_main(
    const float* __restrict__ x,     // [2,32,64,64]
    const float* __restrict__ b1,    // [32]
    const float* __restrict__ bias,  // [32]
    const __hip_bfloat16* __restrict__ ws,
    float* __restrict__ out)         // [2,32,4096]
{
    __shared__ __hip_bfloat16 u_lds[32 * SJ];  // [p][j]
    __shared__ float hh_lds[32 * 33];          // [p][h]
    __shared__ float t_lds[32 * 8];            // [p][o_local] (t+bias)
    __shared__ float o_stage[8][32];           // [o_local][p]

    const int t  = threadIdx.x;
    const int w  = t >> 6;   // wave 0..3
    const int l  = t & 63;
    const int lg = l >> 4;
    const int lr = l & 15;

    const int nt = blockIdx.x & 3, mt = blockIdx.x >> 2;
    const int o0 = nt * 8;            // this block's 8 output channels
    const int g0 = mt * 32;           // first global pixel
    const int b  = g0 >> 12;
    const int l0 = g0 & 4095;
    const int y  = l0 >> 6;
    const int wx0 = l0 & 63;

    // ---- Phase A: fused unfold -> u_lds (bf16) ----
    #pragma unroll
    for (int k = 0; k < 36; ++k) {
        int idx = k * 256 + t;        // 9216 = 32p * 288j
        int j = idx >> 5, p = idx & 31;
        int c = j / 9, r = j - c * 9;
        int ki = r / 3, kj = r - ki * 3;
        int y2 = y + ki - 1;
        int x2 = wx0 + p + kj - 1;
        float v = 0.f;
        if ((unsigned)y2 < 64u && (unsigned)x2 < 64u)
            v = x[((b * 32 + c) * 64 + y2) * 64 + x2];
        u_lds[p * SJ + j] = __float2bfloat16(v);
    }
    __syncthreads();

    // ---- Phase B: waves 0,1 -> hh (W1); wave 2 -> t (b2, 8 cols) ----
    if (w < 3) {
        const __hip_bfloat16* w1b = ws + W1B_OFF;
        const __hip_bfloat16* b2b = ws + B2B_OFF;
        f32x4 acc0 = {0.f,0.f,0.f,0.f}, acc1 = {0.f,0.f,0.f,0.f};
        #pragma unroll
        for (int kb = 0; kb < 9; ++kb) {
            short8 bf;
            if (w < 2)
                bf = *(const short8*)(w1b + (w * 16 + lr) * CKK + kb * 32 + lg * 8);
            else if (lr < 8)
                bf = *(const short8*)(b2b + (o0 + lr) * CKK + kb * 32 + lg * 8);
            else
                bf = short8{0,0,0,0,0,0,0,0};
            short8 a0 = *(const short8*)(u_lds + lr * SJ + kb * 32 + lg * 8);
            short8 a1 = *(const short8*)(u_lds + (16 + lr) * SJ + kb * 32 + lg * 8);
            acc0 = __builtin_amdgcn_mfma_f32_16x16x32_bf16(a0, bf, acc0, 0, 0, 0);
            acc1 = __builtin_amdgcn_mfma_f32_16x16x32_bf16(a1, bf, acc1, 0, 0, 0);
        }
        if (w < 2) {
            const int col = w * 16 + lr;
            float b1v = b1[col];
            #pragma unroll
            for (int r = 0; r < 4; ++r) {
                hh_lds[(lg * 4 + r) * 33 + col]      = tanhf(acc0[r] + b1v);
                hh_lds[(16 + lg * 4 + r) * 33 + col] = tanhf(acc1[r] + b1v);
            }
        } else if (lr < 8) {
            float bv = bias[o0 + lr];
            #pragma unroll
            for (int r = 0; r < 4; ++r) {
                t_lds[(lg * 4 + r) * 8 + lr]      = acc0[r] + bv;
                t_lds[(16 + lg * 4 + r) * 8 + lr] = acc1[r] + bv;
            }
        }
    }
    __syncthreads();

    // ---- Phase C: S GEMM. wave w owns o = o0 + w*2 .. +1 (4 nf of 16) ----
    f32x4 acc[2][4];
    #pragma unroll
    for (int m = 0; m < 2; ++m)
        #pragma unroll
        for (int nf = 0; nf < 4; ++nf)
            acc[m][nf] = f32x4{0.f, 0.f, 0.f, 0.f};

    {
        const __hip_bfloat16* W2f = ws + W2F_OFF;
        const int ckbase = (o0 * 2 + w * 4) * 9;   // chunk index, nf-stride 9
        short8 bcur[4];
        #pragma unroll
        for (int nf = 0; nf < 4; ++nf)
            bcur[nf] = *(const short8*)(W2f + (size_t)(ckbase + nf * 9) * 512 + l * 8);

        #pragma unroll
        for (int kb = 0; kb < 9; ++kb) {
            short8 a0 = *(const short8*)(u_lds + lr * SJ + kb * 32 + lg * 8);
            short8 a1 = *(const short8*)(u_lds + (16 + lr) * SJ + kb * 32 + lg * 8);
            short8 bnext[4];
            if (kb < 8) {
                #pragma unroll
                for (int nf = 0; nf < 4; ++nf)
                    bnext[nf] = *(const short8*)(W2f + (size_t)(ckbase + nf * 9 + kb + 1) * 512 + l * 8);
            }
            #pragma unroll
            for (int nf = 0; nf < 4; ++nf) {
                acc[0][nf] = __builtin_amdgcn_mfma_f32_16x16x32_bf16(a0, bcur[nf], acc[0][nf], 0, 0, 0);
                acc[1][nf] = __builtin_amdgcn_mfma_f32_16x16x32_bf16(a1, bcur[nf], acc[1][nf], 0, 0, 0);
            }
            if (kb < 8) {
                #pragma unroll
                for (int nf = 0; nf < 4; ++nf)
                    bcur[nf] = bnext[nf];
            }
        }
    }

    // ---- Epilogue: out[p,o] = sum_h hh[p,h]*S[p,o,h] ----
    #pragma unroll
    for (int ol = 0; ol < 2; ++ol) {
        const int o_loc = w * 2 + ol;
        #pragma unroll
        for (int m = 0; m < 2; ++m) {
            #pragma unroll
            for (int r = 0; r < 4; ++r) {
                const int p = m * 16 + lg * 4 + r;
                float v = hh_lds[p * 33 + lr]      * acc[m][ol * 2][r]
                        + hh_lds[p * 33 + 16 + lr] * acc[m][ol * 2 + 1][r];
                v += __shfl_xor(v, 1);
                v += __shfl_xor(v, 2);
                v += __shfl_xor(v, 4);
                v += __shfl_xor(v, 8);
                if (lr == 0) o_stage[o_loc][p] = v;
            }
        }
    }
    __syncthreads();

    // ---- Store: 8 o x 32 px, coalesced 128B rows ----
    {
        int o_l = t >> 5, p = t & 31;
        float val = o_stage[o_l][p] + t_lds[p * 8 + o_l];
        out[((size_t)(b * 32 + o0 + o_l)) * 4096 + l0 + p] = val;
    }
}

extern "C" void kernel_launch(void* const* d_in, const int* in_sizes, int n_in,
                              void* d_out, int out_size, void* d_ws, size_t ws_size,
                              hipStream_t stream) {
    const float* x    = (const float*)d_in[0];
    const float* W1   = (const float*)d_in[1];
    const float* b1   = (const float*)d_in[2];
    const float* W2   = (const float*)d_in[3];
    const float* b2   = (const float*)d_in[4];
    const float* bias = (const float*)d_in[5];
    float* out = (float*)d_out;
    __hip_bfloat16* ws = (__hip_bfloat16*)d_ws;

    prep_kernel<<<(WS_ELEMS + 255) / 256, 256, 0, stream>>>(W1, W2, b2, ws);
    dynaconv_main<<<1024, 256, 0, stream>>>(x, b1, bias, ws, out);
}